// Round 9
// baseline (287.932 us; speedup 1.0000x reference)
//
#include <hip/hip_runtime.h>
#include <hip/hip_cooperative_groups.h>
#include <hip/hip_bf16.h>
#include <cmath>

namespace cg = cooperative_groups;

#define T_STEPS 128
#define BATCH   64
#define NI      784
#define NIP     800      // padded K (25 * 32)
#define NH      512
#define NO      10
#define M1      (T_STEPS*BATCH)       // 8192
#define NT_H    (BATCH*NH)            // 32768
#define NT_O    (BATCH*NO)            // 640
#define OUT_HALF (T_STEPS*BATCH*NO)   // 81920
#define TB      8                     // time-tile for the scan

typedef __attribute__((ext_vector_type(8))) short short8;
typedef __attribute__((ext_vector_type(4))) float f32x4;
typedef __attribute__((ext_vector_type(8))) unsigned short u16x8;

static __device__ __forceinline__ unsigned short f2b_bits(float x) {
    __hip_bfloat16 h = __float2bfloat16(x);
    return *reinterpret_cast<unsigned short*>(&h);
}
static __device__ __forceinline__ float b2f_bits(unsigned short u) {
    union { unsigned int i; float f; } v; v.i = ((unsigned int)u) << 16; return v.f;
}

// --- R8 scan body, verbatim (3-LDS-episode tiles + bit-exact zero gates) ----
template <bool FINAL>
__device__ __forceinline__ void flif_scan_body(const char* __restrict__ inps,
                                               float* __restrict__ hist,
                                               const float* __restrict__ cs,
                                               void* __restrict__ spikes,
                                               float* __restrict__ mems,
                                               int NT, int nid, int lane, float kappa) {
    float cn_[TB];
#pragma unroll
    for (int j = 0; j < TB; ++j) cn_[j] = cs[j];

    float V = -70.f;
    unsigned dvbits = 0u;

    for (int t = 0; t < T_STEPS / TB; ++t) {
        const int n0 = t * TB;

        // episode 1: batch input reads (pinned early)
        float Ivv[TB];
#pragma unroll
        for (int i = 0; i < TB; ++i) {
            if constexpr (FINAL) Ivv[i] = ((const float*)inps)[(n0 + i) * 64 + lane];
            else                 Ivv[i] = __bfloat162float(((const __hip_bfloat16*)inps)[(n0 + i) * 64 + lane]);
        }
        __builtin_amdgcn_sched_barrier(0);

        float old_[TB];
#pragma unroll
        for (int i = 0; i < TB; ++i) old_[i] = 0.f;

        // old-phase: skipped (bit-exactly) while history is all +0.0
        if (__any(dvbits != 0u)) {
            for (int k0 = 0; k0 < n0; k0 += TB) {
                float hv[TB];
                unsigned sb = 0u;
#pragma unroll
                for (int kk = 0; kk < TB; ++kk) {
                    hv[kk] = hist[(k0 + kk) * 64 + lane];
                    sb |= __float_as_uint(hv[kk]);
                }
                if (__any(sb != 0u)) {
                    const int base = n0 - k0 - (TB - 1);
                    float cw[2 * TB];
#pragma unroll
                    for (int q = 0; q < 4; ++q) {
                        const float4 cv = *reinterpret_cast<const float4*>(cs + (base - 1) + 4 * q);
                        cw[4 * q + 0] = cv.x; cw[4 * q + 1] = cv.y;
                        cw[4 * q + 2] = cv.z; cw[4 * q + 3] = cv.w;
                    }
#pragma unroll
                    for (int kk = 0; kk < TB; ++kk) {
#pragma unroll
                        for (int i = 0; i < TB; ++i)
                            old_[i] += hv[kk] * cw[TB - kk + i];
                    }
                }
            }
        }

        // episode 2: sequential phase, pure VALU + global stores
        float dvb[TB];
#pragma unroll
        for (int i = 0; i < TB; ++i) {
            const int nm1 = n0 + i;
            const float Iv = Ivv[i];
            const float f  = (-0.025f * (V + 70.f) + Iv) * 2.0f;   // /CM, CM=0.5
            const float Vn = kappa * f + V - old_[i];
            const bool  sp = (Vn >= -50.f);
            const float Vr = sp ? -70.f : Vn;
            const float dv = Vr - V;
            dvb[i] = dv;
            dvbits |= __float_as_uint(dv);
#pragma unroll
            for (int i2 = i + 1; i2 < TB; ++i2)
                old_[i2] += dv * cn_[i2 - i];
            if (FINAL) {
                ((float*)spikes)[(size_t)nm1 * NT + nid] = sp ? 1.f : 0.f;
                mems[(size_t)nm1 * NT + nid] = Vr;
            } else {
                ((__hip_bfloat16*)spikes)[(size_t)nm1 * NT + nid] = __float2bfloat16(sp ? 1.f : 0.f);
            }
            V = Vr;
        }

        // episode 3: batch hist writes
        __builtin_amdgcn_sched_barrier(0);
#pragma unroll
        for (int i = 0; i < TB; ++i)
            hist[(n0 + i) * 64 + lane] = dvb[i];
        __builtin_amdgcn_sched_barrier(0);
    }
}

// ---------------------------------------------------------------------------
// MEGA KERNEL: all 5 pipeline stages in one cooperative dispatch.
// 256 blocks x 256 threads = 1 block/CU (97 KB LDS), grid.sync() between
// stages. Per-stage code is the R8 kernels verbatim.
// LDS carve:
//   [0,16K)  P1 As[2]           | [0,32K) P2-v0 hist / P4 hist
//   [16,32K) P1 Bs[2]           | [32,48K) P2-v0 inp  / P4 inps [32,64K)
//   [48,80K) P2-v1 hist         | [80,96K) P2-v1 inp
//   [96K,96K+768) cs (c-table copy)
// ---------------------------------------------------------------------------
__global__ __launch_bounds__(256) void mega_kernel(const float* __restrict__ data,
                                                   const float* __restrict__ Wh,
                                                   const float* __restrict__ Wo,
                                                   float* __restrict__ out,
                                                   __hip_bfloat16* __restrict__ Ab,
                                                   __hip_bfloat16* __restrict__ Whb,
                                                   __hip_bfloat16* __restrict__ Ih,
                                                   __hip_bfloat16* __restrict__ Sh,
                                                   float* __restrict__ Io,
                                                   float* __restrict__ ctab,
                                                   float kappa) {
    __shared__ __attribute__((aligned(16))) char SMEM[99072];
    cg::grid_group grid = cg::this_grid();

    const int bid  = blockIdx.x;
    const int tid  = threadIdx.x;
    const int wave = tid >> 6, lane = tid & 63;
    float* cs = (float*)(SMEM + 98304);

    // ===== P0: ctab + Ab cast (grid-strided) + Whb cast =====
    if (bid == 0 && tid < 192) {
        double a = pow((double)(tid + 1), 0.8);
        double b = pow((double)tid, 0.8);
        ctab[tid] = (float)(a - b);
    }
#pragma unroll
    for (int i = 0; i < 25; ++i) {                 // 6400 virtual blocks / 256
        const int idx = (bid + 256 * i) * 256 + tid;
        const int r  = idx / 200;
        const int n4 = (idx - r * 200) * 4;
        const int t = r >> 6, b = r & 63;
        const int srow = b * T_STEPS + t;
        ushort4 o;
        if (n4 < NI) {
            const float4 f = *reinterpret_cast<const float4*>(data + (size_t)srow * NI + n4);
            o.x = f2b_bits(f.x); o.y = f2b_bits(f.y); o.z = f2b_bits(f.z); o.w = f2b_bits(f.w);
        } else {
            o.x = o.y = o.z = o.w = 0;
        }
        *reinterpret_cast<ushort4*>(Ab + (size_t)r * NIP + n4) = o;
    }
#pragma unroll
    for (int i = 0; i < 2; ++i) {                  // 400 virtual blocks
        const int vb = bid + 256 * i;
        if (vb < 400) {
            const int idx = vb * 256 + tid;
            const int r  = idx / 200;
            const int n4 = (idx - r * 200) * 4;
            ushort4 o;
            if (n4 < NI) {
                const float4 f = *reinterpret_cast<const float4*>(Wh + (size_t)r * NI + n4);
                o.x = f2b_bits(f.x); o.y = f2b_bits(f.y); o.z = f2b_bits(f.z); o.w = f2b_bits(f.w);
            } else {
                o.x = o.y = o.z = o.w = 0;
            }
            *reinterpret_cast<ushort4*>(Whb + (size_t)r * NIP + n4) = o;
        }
    }
    __threadfence();
    grid.sync();

    // ===== P1: gemm1 (R8 pipelined 128x128), bm=bid&63, bn=bid>>6 =====
    {
        __hip_bfloat16 (*As)[128 * 32] = (__hip_bfloat16(*)[128 * 32])(SMEM);
        __hip_bfloat16 (*Bs)[128 * 32] = (__hip_bfloat16(*)[128 * 32])(SMEM + 16384);
        const int wm = wave >> 1, wn = wave & 1;
        const int bm = bid & 63, bn = bid >> 6;
        const int lrow = lane >> 2;
        const int lchk = lane & 3;
        const int Kp = NIP, N = NH;
        const int NTILES = Kp / 32;

        auto STAGE = [&](int buf, int tt) {
            const int k0 = tt * 32;
#pragma unroll
            for (int p = 0; p < 2; ++p) {
                const int rbase = p * 64 + wave * 16;
                {
                    const __hip_bfloat16* g = Ab + (size_t)(bm * 128 + rbase + lrow) * Kp + k0 + lchk * 8;
                    __builtin_amdgcn_global_load_lds((const __attribute__((address_space(1))) void*)g,
                                                     (__attribute__((address_space(3))) void*)(As[buf] + rbase * 32),
                                                     16, 0, 0);
                }
                {
                    const __hip_bfloat16* g = Whb + (size_t)(bn * 128 + rbase + lrow) * Kp + k0 + lchk * 8;
                    __builtin_amdgcn_global_load_lds((const __attribute__((address_space(1))) void*)g,
                                                     (__attribute__((address_space(3))) void*)(Bs[buf] + rbase * 32),
                                                     16, 0, 0);
                }
            }
        };

        f32x4 acc[4][4] = {};
        STAGE(0, 0);
        __syncthreads();

        int cur = 0;
        for (int t = 0; t < NTILES; ++t) {
            if (t + 1 < NTILES) STAGE(cur ^ 1, t + 1);

            short8 a[4], b[4];
#pragma unroll
            for (int i = 0; i < 4; ++i)
                a[i] = *reinterpret_cast<const short8*>(As[cur] + (wm * 64 + i * 16 + (lane & 15)) * 32 + (lane >> 4) * 8);
#pragma unroll
            for (int j = 0; j < 4; ++j)
                b[j] = *reinterpret_cast<const short8*>(Bs[cur] + (wn * 64 + j * 16 + (lane & 15)) * 32 + (lane >> 4) * 8);
#pragma unroll
            for (int i = 0; i < 4; ++i)
#pragma unroll
                for (int j = 0; j < 4; ++j)
                    acc[i][j] = __builtin_amdgcn_mfma_f32_16x16x32_bf16(a[i], b[j], acc[i][j], 0, 0, 0);

            __syncthreads();
            cur ^= 1;
        }

#pragma unroll
        for (int i = 0; i < 4; ++i) {
#pragma unroll
            for (int j = 0; j < 4; ++j) {
                const int col = bn * 128 + wn * 64 + j * 16 + (lane & 15);
#pragma unroll
                for (int r2 = 0; r2 < 4; ++r2) {
                    const int row = bm * 128 + wm * 64 + i * 16 + (lane >> 4) * 4 + r2;
                    Ih[(size_t)row * N + col] = __float2bfloat16(acc[i][j][r2]);
                }
            }
        }
    }
    __threadfence();
    grid.sync();

    // ===== P2: hidden scan — 2 virtual 64-thread scans per block (waves 0,1)
    {
        if (wave < 2) {
            // stage this virtual scan's input [128][64] bf16 = 16 KB
            char* inp = SMEM + wave * 49152 + 32768;
            const int vb = bid * 2 + wave;
#pragma unroll
            for (int q = 0; q < 16; ++q) {
                const __hip_bfloat16* g = Ih +
                    ((size_t)(q * 8 + (lane >> 3)) * NT_H + (size_t)vb * 64 + (lane & 7) * 8);
                __builtin_amdgcn_global_load_lds((const __attribute__((address_space(1))) void*)g,
                                                 (__attribute__((address_space(3))) void*)(inp + q * 1024),
                                                 16, 0, 0);
            }
        }
        for (int j = tid; j < 192; j += 256) cs[j] = ctab[j];
        __syncthreads();   // drains staging + cs visible to block

        if (wave < 2) {
            float* hist = (float*)(SMEM + wave * 49152);
            char*  inp  = SMEM + wave * 49152 + 32768;
            const int vb  = bid * 2 + wave;
            const int nid = vb * 64 + lane;
            flif_scan_body<false>(inp, hist, cs, Sh, nullptr, NT_H, nid, lane, kappa);
        }
    }
    __threadfence();
    grid.sync();

    // ===== P3: gemm2 — 8 rows per wave (1024 waves) =====
    {
        const int W = bid * 4 + wave;
        const int r0 = W * 8;

        float wreg[NO][8];
#pragma unroll
        for (int o = 0; o < NO; ++o) {
            const float4 w0 = *reinterpret_cast<const float4*>(Wo + (size_t)o * NH + lane * 8);
            const float4 w1 = *reinterpret_cast<const float4*>(Wo + (size_t)o * NH + lane * 8 + 4);
            wreg[o][0] = w0.x; wreg[o][1] = w0.y; wreg[o][2] = w0.z; wreg[o][3] = w0.w;
            wreg[o][4] = w1.x; wreg[o][5] = w1.y; wreg[o][6] = w1.z; wreg[o][7] = w1.w;
        }

#pragma unroll
        for (int rr = 0; rr < 8; ++rr) {
            const int r = r0 + rr;
            u16x8 raw = *reinterpret_cast<const u16x8*>(Sh + (size_t)r * NH + lane * 8);
            float s[8];
#pragma unroll
            for (int j = 0; j < 8; ++j) s[j] = b2f_bits(raw[j]);
#pragma unroll
            for (int o = 0; o < NO; ++o) {
                float a = 0.f;
#pragma unroll
                for (int j = 0; j < 8; ++j) a += s[j] * wreg[o][j];
#pragma unroll
                for (int off = 32; off; off >>= 1) a += __shfl_xor(a, off);
                if (lane == o) Io[(size_t)r * NO + o] = a;
            }
        }
    }
    __threadfence();
    grid.sync();

    // ===== P4: final scan — blocks 0..9, wave 0 =====
    if (bid < 10) {
        char* inps = SMEM + 32768;     // [128][64] f32 = 32 KB
        if (wave == 0) {
#pragma unroll
            for (int q = 0; q < 32; ++q) {
                const float* g = Io +
                    ((size_t)(q * 4 + (lane >> 4)) * NT_O + (size_t)bid * 64 + (lane & 15) * 4);
                __builtin_amdgcn_global_load_lds((const __attribute__((address_space(1))) void*)g,
                                                 (__attribute__((address_space(3))) void*)(inps + q * 1024),
                                                 16, 0, 0);
            }
        }
        for (int j = tid; j < 192; j += 256) cs[j] = ctab[j];
        __syncthreads();

        if (wave == 0) {
            float* hist = (float*)SMEM;
            const int nid = bid * 64 + lane;
            flif_scan_body<true>(inps, hist, cs, out, out + OUT_HALF, NT_O, nid, lane, kappa);
        }
    }
}

extern "C" void kernel_launch(void* const* d_in, const int* in_sizes, int n_in,
                              void* d_out, int out_size, void* d_ws, size_t ws_size,
                              hipStream_t stream) {
    const float* data = (const float*)d_in[0];   // [64][128][784]
    const float* Wh   = (const float*)d_in[1];   // [512][784]
    const float* Wo   = (const float*)d_in[2];   // [10][512]
    float* out = (float*)d_out;                  // f32: spikes then mems

    char* ws = (char*)d_ws;
    size_t off = 0;
    auto alloc = [&](size_t bytes) { void* p = ws + off; off += (bytes + 255) & ~255ull; return p; };
    __hip_bfloat16* Ab   = (__hip_bfloat16*)alloc((size_t)M1 * NIP * 2);  // 13.1 MB
    __hip_bfloat16* Whb  = (__hip_bfloat16*)alloc((size_t)NH * NIP * 2);  // 0.8 MB
    __hip_bfloat16* Ih   = (__hip_bfloat16*)alloc((size_t)M1 * NH * 2);   // 8.4 MB
    __hip_bfloat16* Sh   = (__hip_bfloat16*)alloc((size_t)M1 * NH * 2);   // 8.4 MB
    float*          Io   = (float*)alloc((size_t)M1 * NO * 4);            // 0.33 MB
    float*          ctab = (float*)alloc(192 * 4);

    float kappa = (float)(std::pow(0.1, 0.2) * std::tgamma(1.8));

    void* args[] = {
        (void*)&data, (void*)&Wh, (void*)&Wo, (void*)&out,
        (void*)&Ab, (void*)&Whb, (void*)&Ih, (void*)&Sh, (void*)&Io, (void*)&ctab,
        (void*)&kappa
    };
    hipLaunchCooperativeKernel((const void*)mega_kernel, dim3(256), dim3(256),
                               args, 0, stream);
}

// Round 10
// 94.224 us; speedup vs baseline: 3.0558x; 3.0558x over previous
//
#include <hip/hip_runtime.h>
#include <hip/hip_bf16.h>
#include <cmath>

#define T_STEPS 128
#define BATCH   64
#define NI      784
#define NIP     800      // padded K (25 * 32)
#define NH      512
#define NO      10
#define M1      (T_STEPS*BATCH)       // 8192
#define NT_H    (BATCH*NH)            // 32768
#define NT_O    (BATCH*NO)            // 640
#define OUT_HALF (T_STEPS*BATCH*NO)   // 81920
#define TB      8                     // time-tile for the scan

typedef __attribute__((ext_vector_type(8))) short short8;
typedef __attribute__((ext_vector_type(4))) float f32x4;
typedef __attribute__((ext_vector_type(8))) unsigned short u16x8;

static __device__ __forceinline__ unsigned short f2b_bits(float x) {
    __hip_bfloat16 h = __float2bfloat16(x);
    return *reinterpret_cast<unsigned short*>(&h);
}
static __device__ __forceinline__ float b2f_bits(unsigned short u) {
    union { unsigned int i; float f; } v; v.i = ((unsigned int)u) << 16; return v.f;
}

// --- R8 scan body, generalized over LDS stride and store row-stride ---------
// Stores go to spikes[nm1*NT + nid]; callers encode arbitrary row layouts by
// choosing NT (row stride) and base pointer. Bit-exact zero-history gates,
// 3-LDS-episode structure (R8, verified at 69.5 us).
template <bool FINAL, int STRIDE>
__device__ __forceinline__ void flif_scan_body(const char* __restrict__ inps,
                                               float* __restrict__ hist,
                                               const float* __restrict__ cs,
                                               void* __restrict__ spikes,
                                               float* __restrict__ mems,
                                               int NT, int nid, int li, float kappa) {
    float cn_[TB];
#pragma unroll
    for (int j = 0; j < TB; ++j) cn_[j] = cs[j];

    float V = -70.f;
    unsigned dvbits = 0u;

    for (int t = 0; t < T_STEPS / TB; ++t) {
        const int n0 = t * TB;

        // episode 1: batch input reads (pinned early)
        float Ivv[TB];
#pragma unroll
        for (int i = 0; i < TB; ++i) {
            if constexpr (FINAL) Ivv[i] = ((const float*)inps)[(n0 + i) * STRIDE + li];
            else                 Ivv[i] = __bfloat162float(((const __hip_bfloat16*)inps)[(n0 + i) * STRIDE + li]);
        }
        __builtin_amdgcn_sched_barrier(0);

        float old_[TB];
#pragma unroll
        for (int i = 0; i < TB; ++i) old_[i] = 0.f;

        // old-phase: skipped (bit-exactly) while history is all +0.0
        if (__any(dvbits != 0u)) {
            for (int k0 = 0; k0 < n0; k0 += TB) {
                float hv[TB];
                unsigned sb = 0u;
#pragma unroll
                for (int kk = 0; kk < TB; ++kk) {
                    hv[kk] = hist[(k0 + kk) * STRIDE + li];
                    sb |= __float_as_uint(hv[kk]);
                }
                if (__any(sb != 0u)) {
                    const int base = n0 - k0 - (TB - 1);
                    float cw[2 * TB];
#pragma unroll
                    for (int q = 0; q < 4; ++q) {
                        const float4 cv = *reinterpret_cast<const float4*>(cs + (base - 1) + 4 * q);
                        cw[4 * q + 0] = cv.x; cw[4 * q + 1] = cv.y;
                        cw[4 * q + 2] = cv.z; cw[4 * q + 3] = cv.w;
                    }
#pragma unroll
                    for (int kk = 0; kk < TB; ++kk) {
#pragma unroll
                        for (int i = 0; i < TB; ++i)
                            old_[i] += hv[kk] * cw[TB - kk + i];
                    }
                }
            }
        }

        // episode 2: sequential phase, pure VALU + global stores
        float dvb[TB];
#pragma unroll
        for (int i = 0; i < TB; ++i) {
            const int nm1 = n0 + i;
            const float Iv = Ivv[i];
            const float f  = (-0.025f * (V + 70.f) + Iv) * 2.0f;   // /CM, CM=0.5
            const float Vn = kappa * f + V - old_[i];
            const bool  sp = (Vn >= -50.f);
            const float Vr = sp ? -70.f : Vn;
            const float dv = Vr - V;
            dvb[i] = dv;
            dvbits |= __float_as_uint(dv);
#pragma unroll
            for (int i2 = i + 1; i2 < TB; ++i2)
                old_[i2] += dv * cn_[i2 - i];
            if (FINAL) {
                ((float*)spikes)[(size_t)nm1 * NT + nid] = sp ? 1.f : 0.f;
                mems[(size_t)nm1 * NT + nid] = Vr;
            } else {
                ((__hip_bfloat16*)spikes)[(size_t)nm1 * NT + nid] = __float2bfloat16(sp ? 1.f : 0.f);
            }
            V = Vr;
        }

        // episode 3: batch hist writes
        __builtin_amdgcn_sched_barrier(0);
#pragma unroll
        for (int i = 0; i < TB; ++i)
            hist[(n0 + i) * STRIDE + li] = dvb[i];
        __builtin_amdgcn_sched_barrier(0);
    }
}

// ---------------------------------------------------------------------------
// FUSED kernel 1: cast + GEMM1 + hidden scan, per (batch b, neuron-block hn).
// data's native layout [b*128+t][784] IS the GEMM A layout when M-tiles = one
// batch element x all 128 timesteps; the 128x128 (t x h) I-tile never touches
// HBM: MFMA -> LDS bf16 (identical cast to the old Ih path) -> in-block scan
// by waves 0-1, spikes written straight to Sh[(t*64+b)*NH + col] via the
// body's NT=64*NH / base=Sh+b*NH encoding.
// LDS (128 KB): [0,16K) As | [16,32K) Bs | post-GEMM [0,768) cs
//               [32,64K) Ibuf bf16[128][128] | [64,128K) hist f32[128][128]
// Grid (64,4): linear id = b + 64*hn -> same-b blocks share an XCD.
// ---------------------------------------------------------------------------
__global__ __launch_bounds__(256) void fused1_kernel(const float* __restrict__ data,
                                                     const float* __restrict__ Wh,
                                                     __hip_bfloat16* __restrict__ Sh,
                                                     const float* __restrict__ ctab,
                                                     float kappa) {
    __shared__ __attribute__((aligned(16))) char SMEM[131072];
    __hip_bfloat16* As   = (__hip_bfloat16*)SMEM;             // [128][32]
    __hip_bfloat16* Bs   = (__hip_bfloat16*)(SMEM + 16384);   // [128][32]
    __hip_bfloat16* Ibuf = (__hip_bfloat16*)(SMEM + 32768);   // [128][128]
    float*          hist = (float*)(SMEM + 65536);            // [128][128]
    float*          cs   = (float*)SMEM;                      // overlaps As (post-GEMM)

    const int tid  = threadIdx.x;
    const int wave = tid >> 6, lane = tid & 63;
    const int wm = wave >> 1, wn = wave & 1;
    const int b  = blockIdx.x;     // batch element
    const int hn = blockIdx.y;     // 128-wide neuron block

    const int NTILES = NIP / 32;   // 25

    float4 ra[4], rb[4];
    auto LOADT = [&](int t) {
        const int k0 = t * 32;
#pragma unroll
        for (int q = 0; q < 4; ++q) {
            const int idx = tid + 256 * q;       // 0..1023
            const int row = idx >> 3;            // 0..127
            const int c4  = idx & 7;
            const int gk  = k0 + c4 * 4;
            if (gk < NI) {                       // 784 % 4 == 0: full float4 valid
                ra[q] = *reinterpret_cast<const float4*>(data + (size_t)(b * 128 + row) * NI + gk);
                rb[q] = *reinterpret_cast<const float4*>(Wh   + (size_t)(hn * 128 + row) * NI + gk);
            } else {
                ra[q] = make_float4(0.f, 0.f, 0.f, 0.f);
                rb[q] = make_float4(0.f, 0.f, 0.f, 0.f);
            }
        }
    };
    auto WRITET = [&]() {
#pragma unroll
        for (int q = 0; q < 4; ++q) {
            const int idx = tid + 256 * q;
            const int row = idx >> 3;
            const int c4  = idx & 7;
            ushort4 oa, ob;
            oa.x = f2b_bits(ra[q].x); oa.y = f2b_bits(ra[q].y);
            oa.z = f2b_bits(ra[q].z); oa.w = f2b_bits(ra[q].w);
            ob.x = f2b_bits(rb[q].x); ob.y = f2b_bits(rb[q].y);
            ob.z = f2b_bits(rb[q].z); ob.w = f2b_bits(rb[q].w);
            *reinterpret_cast<ushort4*>(As + row * 32 + c4 * 4) = oa;
            *reinterpret_cast<ushort4*>(Bs + row * 32 + c4 * 4) = ob;
        }
    };

    f32x4 acc[4][4] = {};

    LOADT(0);
    WRITET();
    __syncthreads();

    for (int t = 0; t < NTILES; ++t) {
        if (t + 1 < NTILES) LOADT(t + 1);        // global loads in flight over MFMA
        __builtin_amdgcn_sched_barrier(0);       // pin load issue before compute

        short8 a[4], bfr[4];
#pragma unroll
        for (int i = 0; i < 4; ++i)
            a[i] = *reinterpret_cast<const short8*>(As + (wm * 64 + i * 16 + (lane & 15)) * 32 + (lane >> 4) * 8);
#pragma unroll
        for (int j = 0; j < 4; ++j)
            bfr[j] = *reinterpret_cast<const short8*>(Bs + (wn * 64 + j * 16 + (lane & 15)) * 32 + (lane >> 4) * 8);
#pragma unroll
        for (int i = 0; i < 4; ++i)
#pragma unroll
            for (int j = 0; j < 4; ++j)
                acc[i][j] = __builtin_amdgcn_mfma_f32_16x16x32_bf16(a[i], bfr[j], acc[i][j], 0, 0, 0);

        __syncthreads();                         // LDS reads of tile t done
        if (t + 1 < NTILES) {
            WRITET();                            // stage tile t+1
            __syncthreads();                     // writes visible
        }
    }

    // I tile -> LDS bf16 (same cast as the old Ih global write; row=t, col=h)
#pragma unroll
    for (int i = 0; i < 4; ++i) {
#pragma unroll
        for (int j = 0; j < 4; ++j) {
            const int col = wn * 64 + j * 16 + (lane & 15);
#pragma unroll
            for (int r2 = 0; r2 < 4; ++r2) {
                const int row = wm * 64 + i * 16 + (lane >> 4) * 4 + r2;
                Ibuf[row * 128 + col] = __float2bfloat16(acc[i][j][r2]);
            }
        }
    }
    __syncthreads();                             // Ibuf complete; As region dead

    for (int j = tid; j < 192; j += 256) cs[j] = ctab[j];
    __syncthreads();

    // hidden scan: waves 0-1, one thread per neuron column.
    // Store target: Sh[(t*64+b)*NH + hn*128 + tid] == base (Sh + b*NH),
    // NT = 64*NH (row stride per t), nid = hn*128 + tid.
    if (tid < 128) {
        flif_scan_body<false, 128>((const char*)Ibuf, hist, cs,
                                   (void*)(Sh + (size_t)b * NH), nullptr,
                                   64 * NH, hn * 128 + tid, tid, kappa);
    }
}

// --- GEMM2: Io[r][o] = sum_h S[r][h]*Wo[o][h] (R8 version) ------------------
__global__ __launch_bounds__(256) void gemm2_kernel(const __hip_bfloat16* __restrict__ S,
                                                    const float* __restrict__ Wo,
                                                    float* __restrict__ Io) {
    const int wave = threadIdx.x >> 6, lane = threadIdx.x & 63;
    const int r0 = (blockIdx.x * 4 + wave) * 4;

    float wreg[NO][8];
#pragma unroll
    for (int o = 0; o < NO; ++o) {
        const float4 w0 = *reinterpret_cast<const float4*>(Wo + (size_t)o * NH + lane * 8);
        const float4 w1 = *reinterpret_cast<const float4*>(Wo + (size_t)o * NH + lane * 8 + 4);
        wreg[o][0] = w0.x; wreg[o][1] = w0.y; wreg[o][2] = w0.z; wreg[o][3] = w0.w;
        wreg[o][4] = w1.x; wreg[o][5] = w1.y; wreg[o][6] = w1.z; wreg[o][7] = w1.w;
    }

#pragma unroll
    for (int rr = 0; rr < 4; ++rr) {
        const int r = r0 + rr;
        u16x8 raw = *reinterpret_cast<const u16x8*>(S + (size_t)r * NH + lane * 8);
        float s[8];
#pragma unroll
        for (int j = 0; j < 8; ++j) s[j] = b2f_bits(raw[j]);
#pragma unroll
        for (int o = 0; o < NO; ++o) {
            float a = 0.f;
#pragma unroll
            for (int j = 0; j < 8; ++j) a += s[j] * wreg[o][j];
#pragma unroll
            for (int off = 32; off; off >>= 1) a += __shfl_xor(a, off);
            if (lane == o) Io[(size_t)r * NO + o] = a;
        }
    }
}

// --- final scan: R8 version (LDS-staged f32 input, STRIDE=64) ---------------
__global__ __launch_bounds__(64) void flif_final_kernel(const float* __restrict__ Io,
                                                        float* __restrict__ spikes,
                                                        float* __restrict__ mems,
                                                        const float* __restrict__ ctab,
                                                        float kappa) {
    __shared__ float hist[T_STEPS * 64];                       // 32 KB
    __shared__ __attribute__((aligned(16))) float cs[192];
    __shared__ __attribute__((aligned(16))) char inps[T_STEPS * 64 * 4];  // 32 KB
    const int lane = threadIdx.x;
    const int nid  = blockIdx.x * 64 + lane;

#pragma unroll
    for (int q = 0; q < 32; ++q) {
        const float* g = Io +
            ((size_t)(q * 4 + (lane >> 4)) * NT_O + (size_t)blockIdx.x * 64 + (lane & 15) * 4);
        __builtin_amdgcn_global_load_lds((const __attribute__((address_space(1))) void*)g,
                                         (__attribute__((address_space(3))) void*)(inps + q * 1024),
                                         16, 0, 0);
    }
    for (int j = lane; j < 192; j += 64) cs[j] = ctab[j];
    __syncthreads();

    flif_scan_body<true, 64>(inps, hist, cs, spikes, mems, NT_O, nid, lane, kappa);
}

extern "C" void kernel_launch(void* const* d_in, const int* in_sizes, int n_in,
                              void* d_out, int out_size, void* d_ws, size_t ws_size,
                              hipStream_t stream) {
    const float* data = (const float*)d_in[0];   // [64][128][784]
    const float* Wh   = (const float*)d_in[1];   // [512][784]
    const float* Wo   = (const float*)d_in[2];   // [10][512]
    float* out = (float*)d_out;                  // f32: spikes then mems

    char* ws = (char*)d_ws;
    size_t off = 0;
    auto alloc = [&](size_t bytes) { void* p = ws + off; off += (bytes + 255) & ~255ull; return p; };
    __hip_bfloat16* Sh   = (__hip_bfloat16*)alloc((size_t)M1 * NH * 2);   // 8.4 MB
    float*          Io   = (float*)alloc((size_t)M1 * NO * 4);            // 0.33 MB
    float*          ctab = (float*)alloc(192 * 4);

    const float kappa = (float)(std::pow(0.1, 0.2) * std::tgamma(1.8));

    // c table on host (same double-pow math as the old init kernel); static
    // storage keeps the pointer valid under graph capture.
    static float h_ctab[192];
    for (int j = 0; j < 192; ++j)
        h_ctab[j] = (float)(std::pow((double)(j + 1), 0.8) - std::pow((double)j, 0.8));
    hipMemcpyAsync(ctab, h_ctab, 192 * sizeof(float), hipMemcpyHostToDevice, stream);

    dim3 g1(BATCH, NH / 128, 1);    // (64, 4)
    fused1_kernel<<<g1, 256, 0, stream>>>(data, Wh, Sh, ctab, kappa);

    gemm2_kernel<<<M1 / 16, 256, 0, stream>>>(Sh, Wo, Io);

    flif_final_kernel<<<NT_O / 64, 64, 0, stream>>>(Io, out, out + OUT_HALF, ctab, kappa);
}

// Round 11
// 64.955 us; speedup vs baseline: 4.4328x; 1.4506x over previous
//
#include <hip/hip_runtime.h>
#include <hip/hip_bf16.h>
#include <cmath>

#define T_STEPS 128
#define BATCH   64
#define NI      784
#define NIP     800      // padded K (25 * 32)
#define NH      512
#define NO      10
#define M1      (T_STEPS*BATCH)       // 8192
#define NT_H    (BATCH*NH)            // 32768
#define NT_O    (BATCH*NO)            // 640
#define OUT_HALF (T_STEPS*BATCH*NO)   // 81920
#define TB      8                     // time-tile for the scan

typedef __attribute__((ext_vector_type(8))) short short8;
typedef __attribute__((ext_vector_type(4))) float f32x4;
typedef __attribute__((ext_vector_type(8))) unsigned short u16x8;

static __device__ __forceinline__ unsigned short f2b_bits(float x) {
    __hip_bfloat16 h = __float2bfloat16(x);
    return *reinterpret_cast<unsigned short*>(&h);
}
static __device__ __forceinline__ float b2f_bits(unsigned short u) {
    union { unsigned int i; float f; } v; v.i = ((unsigned int)u) << 16; return v.f;
}

// --- prep: fused ctab init + data cast/permute + Wh cast (R8, proven) -------
__global__ __launch_bounds__(256) void prep_kernel(const float* __restrict__ data,
                                                   const float* __restrict__ Wh,
                                                   __hip_bfloat16* __restrict__ Ab,
                                                   __hip_bfloat16* __restrict__ Whb,
                                                   float* __restrict__ ctab) {
    const int bid = blockIdx.x;
    if (bid == 0) {
        const int j = threadIdx.x;
        if (j < 192) {
            double a = pow((double)(j + 1), 0.8);
            double b = pow((double)j, 0.8);
            ctab[j] = (float)(a - b);
        }
        return;
    }
    if (bid <= 6400) {
        const int idx = (bid - 1) * 256 + threadIdx.x;      // < M1*200 exactly
        const int r  = idx / 200;
        const int n4 = (idx - r * 200) * 4;
        const int t = r >> 6, b = r & 63;
        const int srow = b * T_STEPS + t;
        ushort4 o;
        if (n4 < NI) {
            const float4 f = *reinterpret_cast<const float4*>(data + (size_t)srow * NI + n4);
            o.x = f2b_bits(f.x); o.y = f2b_bits(f.y); o.z = f2b_bits(f.z); o.w = f2b_bits(f.w);
        } else {
            o.x = o.y = o.z = o.w = 0;
        }
        *reinterpret_cast<ushort4*>(Ab + (size_t)r * NIP + n4) = o;
    } else {
        const int idx = (bid - 6401) * 256 + threadIdx.x;   // < NH*200 exactly
        const int r  = idx / 200;
        const int n4 = (idx - r * 200) * 4;
        ushort4 o;
        if (n4 < NI) {
            const float4 f = *reinterpret_cast<const float4*>(Wh + (size_t)r * NI + n4);
            o.x = f2b_bits(f.x); o.y = f2b_bits(f.y); o.z = f2b_bits(f.z); o.w = f2b_bits(f.w);
        } else {
            o.x = o.y = o.z = o.w = 0;
        }
        *reinterpret_cast<ushort4*>(Whb + (size_t)r * NIP + n4) = o;
    }
}

// --- bf16 MFMA GEMM: C[M][N] = A[M][Kp] * B[N][Kp]^T ------------------------
// RETILED 64x128 (was 128x128): grid (128,4) = 512 blocks = 2 blocks/CU, so
// one block's MFMA phase overlaps the other's vmcnt(0) staging drain (the
// 1-block/CU version serialized a full HBM latency per K-tile with nothing
// to hide it). acc shrinks 64->32 VGPRs (R10 showed 132-VGPR spill cliff).
// Same-bm blocks are 128 apart in linear id (128%8==0) -> same XCD -> the
// A-band stays L2-local. K-accumulation order per output element unchanged
// -> bit-identical C. Double-buffered global_load_lds staging as in R8.
__global__ __launch_bounds__(256) void gemm_bf16_kernel(const __hip_bfloat16* __restrict__ A,
                                                        const __hip_bfloat16* __restrict__ B,
                                                        __hip_bfloat16* __restrict__ C,
                                                        int N, int Kp) {
    __shared__ __hip_bfloat16 As[2][64 * 32];    //  8 KB
    __shared__ __hip_bfloat16 Bs[2][128 * 32];   // 16 KB
    const int tid  = threadIdx.x;
    const int wave = tid >> 6, lane = tid & 63;
    const int wm = wave >> 1, wn = wave & 1;     // waves 2x2 over (32 rows, 64 cols)
    const int bm = blockIdx.x, bn = blockIdx.y;  // (0..127, 0..3)
    const int lrow = lane >> 2;      // 0..15
    const int lchk = lane & 3;       // 0..3

    const int NTILES = Kp / 32;      // 25

    auto STAGE = [&](int buf, int tt) {
        const int k0 = tt * 32;
        {   // A tile 64x32: wave w stages rows w*16..+15 (one load)
            const __hip_bfloat16* g = A + (size_t)(bm * 64 + wave * 16 + lrow) * Kp + k0 + lchk * 8;
            __builtin_amdgcn_global_load_lds((const __attribute__((address_space(1))) void*)g,
                                             (__attribute__((address_space(3))) void*)(As[buf] + wave * 16 * 32),
                                             16, 0, 0);
        }
#pragma unroll
        for (int p = 0; p < 2; ++p) {   // B tile 128x32: two stripes per wave
            const int rbase = p * 64 + wave * 16;
            const __hip_bfloat16* g = B + (size_t)(bn * 128 + rbase + lrow) * Kp + k0 + lchk * 8;
            __builtin_amdgcn_global_load_lds((const __attribute__((address_space(1))) void*)g,
                                             (__attribute__((address_space(3))) void*)(Bs[buf] + rbase * 32),
                                             16, 0, 0);
        }
    };

    f32x4 acc[2][4] = {};

    STAGE(0, 0);
    __syncthreads();                 // drains vmcnt(0): buf0 ready

    int cur = 0;
    for (int t = 0; t < NTILES; ++t) {
        if (t + 1 < NTILES) STAGE(cur ^ 1, t + 1);   // loads in flight over MFMA

        short8 a[2], b[4];
#pragma unroll
        for (int i = 0; i < 2; ++i)
            a[i] = *reinterpret_cast<const short8*>(As[cur] + (wm * 32 + i * 16 + (lane & 15)) * 32 + (lane >> 4) * 8);
#pragma unroll
        for (int j = 0; j < 4; ++j)
            b[j] = *reinterpret_cast<const short8*>(Bs[cur] + (wn * 64 + j * 16 + (lane & 15)) * 32 + (lane >> 4) * 8);
#pragma unroll
        for (int i = 0; i < 2; ++i)
#pragma unroll
            for (int j = 0; j < 4; ++j)
                acc[i][j] = __builtin_amdgcn_mfma_f32_16x16x32_bf16(a[i], b[j], acc[i][j], 0, 0, 0);

        __syncthreads();             // drains next-tile loads + all reads of cur
        cur ^= 1;
    }

    // C/D layout: col = lane&15, row = (lane>>4)*4 + reg
#pragma unroll
    for (int i = 0; i < 2; ++i) {
#pragma unroll
        for (int j = 0; j < 4; ++j) {
            const int col = bn * 128 + wn * 64 + j * 16 + (lane & 15);
#pragma unroll
            for (int r2 = 0; r2 < 4; ++r2) {
                const int row = bm * 64 + wm * 32 + i * 16 + (lane >> 4) * 4 + r2;
                C[(size_t)row * N + col] = __float2bfloat16(acc[i][j][r2]);
            }
        }
    }
}

// --- fractional LIF scan: R8 version verbatim (3-LDS-episode tiles + gates) -
template <bool FINAL>
__global__ __launch_bounds__(64) void flif_scan_kernel(const void* __restrict__ Iin,
                                                       void* __restrict__ spikes,
                                                       float* __restrict__ mems,
                                                       const float* __restrict__ ctab,
                                                       int NT, float kappa) {
    __shared__ float hist[T_STEPS * 64];        // [k][lane], 32 KB
    __shared__ __attribute__((aligned(16))) float cs[192];
    __shared__ __attribute__((aligned(16))) char inps[FINAL ? T_STEPS * 64 * 4 : T_STEPS * 64 * 2];
    const int lane = threadIdx.x;
    const int nid  = blockIdx.x * 64 + lane;

    if constexpr (!FINAL) {
#pragma unroll
        for (int q = 0; q < 16; ++q) {
            const __hip_bfloat16* g = (const __hip_bfloat16*)Iin +
                ((size_t)(q * 8 + (lane >> 3)) * NT + (size_t)blockIdx.x * 64 + (lane & 7) * 8);
            __builtin_amdgcn_global_load_lds((const __attribute__((address_space(1))) void*)g,
                                             (__attribute__((address_space(3))) void*)(inps + q * 1024),
                                             16, 0, 0);
        }
    } else {
#pragma unroll
        for (int q = 0; q < 32; ++q) {
            const float* g = (const float*)Iin +
                ((size_t)(q * 4 + (lane >> 4)) * NT + (size_t)blockIdx.x * 64 + (lane & 15) * 4);
            __builtin_amdgcn_global_load_lds((const __attribute__((address_space(1))) void*)g,
                                             (__attribute__((address_space(3))) void*)(inps + q * 1024),
                                             16, 0, 0);
        }
    }

    for (int j = lane; j < 192; j += 64) cs[j] = ctab[j];
    __syncthreads();   // drains staging (vmcnt 0) + cs visible

    float cn_[TB];
#pragma unroll
    for (int j = 0; j < TB; ++j) cn_[j] = cs[j];

    float V = -70.f;
    unsigned dvbits = 0u;

    for (int t = 0; t < T_STEPS / TB; ++t) {
        const int n0 = t * TB;

        // episode 1: batch input reads (pinned early)
        float Ivv[TB];
#pragma unroll
        for (int i = 0; i < TB; ++i) {
            if constexpr (FINAL) Ivv[i] = ((const float*)inps)[(n0 + i) * 64 + lane];
            else                 Ivv[i] = __bfloat162float(((const __hip_bfloat16*)inps)[(n0 + i) * 64 + lane]);
        }
        __builtin_amdgcn_sched_barrier(0);

        float old_[TB];
#pragma unroll
        for (int i = 0; i < TB; ++i) old_[i] = 0.f;

        // old-phase: skipped (bit-exactly) while history is all +0.0
        if (__any(dvbits != 0u)) {
            for (int k0 = 0; k0 < n0; k0 += TB) {
                float hv[TB];
                unsigned sb = 0u;
#pragma unroll
                for (int kk = 0; kk < TB; ++kk) {
                    hv[kk] = hist[(k0 + kk) * 64 + lane];
                    sb |= __float_as_uint(hv[kk]);
                }
                if (__any(sb != 0u)) {
                    const int base = n0 - k0 - (TB - 1);   // >=1; base-1 multiple of 8
                    float cw[2 * TB];                      // cw[j] = c[base-1+j]
#pragma unroll
                    for (int q = 0; q < 4; ++q) {
                        const float4 cv = *reinterpret_cast<const float4*>(cs + (base - 1) + 4 * q);
                        cw[4 * q + 0] = cv.x; cw[4 * q + 1] = cv.y;
                        cw[4 * q + 2] = cv.z; cw[4 * q + 3] = cv.w;
                    }
#pragma unroll
                    for (int kk = 0; kk < TB; ++kk) {
#pragma unroll
                        for (int i = 0; i < TB; ++i)
                            old_[i] += hv[kk] * cw[TB - kk + i];
                    }
                }
            }
        }

        // episode 2: sequential phase, pure VALU + global stores
        float dvb[TB];
#pragma unroll
        for (int i = 0; i < TB; ++i) {
            const int nm1 = n0 + i;
            const float Iv = Ivv[i];
            const float f  = (-0.025f * (V + 70.f) + Iv) * 2.0f;   // /CM, CM=0.5
            const float Vn = kappa * f + V - old_[i];
            const bool  sp = (Vn >= -50.f);
            const float Vr = sp ? -70.f : Vn;
            const float dv = Vr - V;
            dvb[i] = dv;
            dvbits |= __float_as_uint(dv);
#pragma unroll
            for (int i2 = i + 1; i2 < TB; ++i2)
                old_[i2] += dv * cn_[i2 - i];
            if (FINAL) {
                ((float*)spikes)[(size_t)nm1 * NT + nid] = sp ? 1.f : 0.f;
                mems[(size_t)nm1 * NT + nid] = Vr;
            } else {
                ((__hip_bfloat16*)spikes)[(size_t)nm1 * NT + nid] = __float2bfloat16(sp ? 1.f : 0.f);
            }
            V = Vr;
        }

        // episode 3: batch hist writes
        __builtin_amdgcn_sched_barrier(0);
#pragma unroll
        for (int i = 0; i < TB; ++i)
            hist[(n0 + i) * 64 + lane] = dvb[i];
        __builtin_amdgcn_sched_barrier(0);
    }
}

// --- GEMM2: Io[r][o] = sum_h S[r][h]*Wo[o][h] (R8 version) ------------------
__global__ __launch_bounds__(256) void gemm2_kernel(const __hip_bfloat16* __restrict__ S,
                                                    const float* __restrict__ Wo,
                                                    float* __restrict__ Io) {
    const int wave = threadIdx.x >> 6, lane = threadIdx.x & 63;
    const int r0 = (blockIdx.x * 4 + wave) * 4;

    float wreg[NO][8];
#pragma unroll
    for (int o = 0; o < NO; ++o) {
        const float4 w0 = *reinterpret_cast<const float4*>(Wo + (size_t)o * NH + lane * 8);
        const float4 w1 = *reinterpret_cast<const float4*>(Wo + (size_t)o * NH + lane * 8 + 4);
        wreg[o][0] = w0.x; wreg[o][1] = w0.y; wreg[o][2] = w0.z; wreg[o][3] = w0.w;
        wreg[o][4] = w1.x; wreg[o][5] = w1.y; wreg[o][6] = w1.z; wreg[o][7] = w1.w;
    }

#pragma unroll
    for (int rr = 0; rr < 4; ++rr) {
        const int r = r0 + rr;
        u16x8 raw = *reinterpret_cast<const u16x8*>(S + (size_t)r * NH + lane * 8);
        float s[8];
#pragma unroll
        for (int j = 0; j < 8; ++j) s[j] = b2f_bits(raw[j]);
#pragma unroll
        for (int o = 0; o < NO; ++o) {
            float a = 0.f;
#pragma unroll
            for (int j = 0; j < 8; ++j) a += s[j] * wreg[o][j];
#pragma unroll
            for (int off = 32; off; off >>= 1) a += __shfl_xor(a, off);
            if (lane == o) Io[(size_t)r * NO + o] = a;
        }
    }
}

extern "C" void kernel_launch(void* const* d_in, const int* in_sizes, int n_in,
                              void* d_out, int out_size, void* d_ws, size_t ws_size,
                              hipStream_t stream) {
    const float* data = (const float*)d_in[0];   // [64][128][784]
    const float* Wh   = (const float*)d_in[1];   // [512][784]
    const float* Wo   = (const float*)d_in[2];   // [10][512]
    float* out = (float*)d_out;                  // f32: spikes then mems

    char* ws = (char*)d_ws;
    size_t off = 0;
    auto alloc = [&](size_t bytes) { void* p = ws + off; off += (bytes + 255) & ~255ull; return p; };
    __hip_bfloat16* Ab   = (__hip_bfloat16*)alloc((size_t)M1 * NIP * 2);  // 13.1 MB
    __hip_bfloat16* Whb  = (__hip_bfloat16*)alloc((size_t)NH * NIP * 2);  // 0.8 MB
    __hip_bfloat16* Ih   = (__hip_bfloat16*)alloc((size_t)M1 * NH * 2);   // 8.4 MB
    __hip_bfloat16* Sh   = (__hip_bfloat16*)alloc((size_t)M1 * NH * 2);   // 8.4 MB
    float*          Io   = (float*)alloc((size_t)M1 * NO * 4);            // 0.33 MB
    float*          ctab = (float*)alloc(192 * 4);

    const float kappa = (float)(std::pow(0.1, 0.2) * std::tgamma(1.8));

    prep_kernel<<<6801, 256, 0, stream>>>(data, Wh, Ab, Whb, ctab);

    dim3 g1(M1 / 64, NH / 128, 1);   // (128, 4) = 512 blocks = 2 blocks/CU
    gemm_bf16_kernel<<<g1, 256, 0, stream>>>(Ab, Whb, Ih, NH, NIP);

    flif_scan_kernel<false><<<NT_H / 64, 64, 0, stream>>>(Ih, Sh, nullptr, ctab, NT_H, kappa);

    gemm2_kernel<<<M1 / 16, 256, 0, stream>>>(Sh, Wo, Io);

    flif_scan_kernel<true><<<NT_O / 64, 64, 0, stream>>>(Io, out, out + OUT_HALF, ctab, NT_O, kappa);
}

// Round 12
// 63.536 us; speedup vs baseline: 4.5318x; 1.0223x over previous
//
#include <hip/hip_runtime.h>
#include <hip/hip_bf16.h>
#include <cmath>

#define T_STEPS 128
#define BATCH   64
#define NI      784
#define NIP     800      // padded K (25 * 32)
#define NH      512
#define NO      10
#define M1      (T_STEPS*BATCH)       // 8192
#define NT_H    (BATCH*NH)            // 32768
#define NT_O    (BATCH*NO)            // 640
#define OUT_HALF (T_STEPS*BATCH*NO)   // 81920
#define TB      8                     // time-tile for the scan

typedef __attribute__((ext_vector_type(8))) short short8;
typedef __attribute__((ext_vector_type(4))) float f32x4;
typedef __attribute__((ext_vector_type(8))) unsigned short u16x8;

static __device__ __forceinline__ unsigned short f2b_bits(float x) {
    __hip_bfloat16 h = __float2bfloat16(x);
    return *reinterpret_cast<unsigned short*>(&h);
}
static __device__ __forceinline__ float b2f_bits(unsigned short u) {
    union { unsigned int i; float f; } v; v.i = ((unsigned int)u) << 16; return v.f;
}

// --- R8 scan body (verbatim arithmetic), shared by fused1 and scanF ---------
// inps: LDS input [t*STRIDE + li] (bf16 if !FINAL, f32 if FINAL)
// hist: LDS [t*STRIDE + li] f32
// Stores: spikes[nm1*NT + nid] (+ mems if FINAL); callers encode row layout
// via NT/base. 3-LDS-episode tiles + bit-exact zero-history gates.
template <bool FINAL, int STRIDE>
__device__ __forceinline__ void flif_scan_body(const char* __restrict__ inps,
                                               float* __restrict__ hist,
                                               const float* __restrict__ cs,
                                               void* __restrict__ spikes,
                                               float* __restrict__ mems,
                                               int NT, int nid, int li, float kappa) {
    float cn_[TB];
#pragma unroll
    for (int j = 0; j < TB; ++j) cn_[j] = cs[j];

    float V = -70.f;
    unsigned dvbits = 0u;

    for (int t = 0; t < T_STEPS / TB; ++t) {
        const int n0 = t * TB;

        // episode 1: batch input reads (pinned early)
        float Ivv[TB];
#pragma unroll
        for (int i = 0; i < TB; ++i) {
            if constexpr (FINAL) Ivv[i] = ((const float*)inps)[(n0 + i) * STRIDE + li];
            else                 Ivv[i] = __bfloat162float(((const __hip_bfloat16*)inps)[(n0 + i) * STRIDE + li]);
        }
        __builtin_amdgcn_sched_barrier(0);

        float old_[TB];
#pragma unroll
        for (int i = 0; i < TB; ++i) old_[i] = 0.f;

        // old-phase: skipped (bit-exactly) while history is all +0.0
        if (__any(dvbits != 0u)) {
            for (int k0 = 0; k0 < n0; k0 += TB) {
                float hv[TB];
                unsigned sb = 0u;
#pragma unroll
                for (int kk = 0; kk < TB; ++kk) {
                    hv[kk] = hist[(k0 + kk) * STRIDE + li];
                    sb |= __float_as_uint(hv[kk]);
                }
                if (__any(sb != 0u)) {
                    const int base = n0 - k0 - (TB - 1);   // >=1; base-1 multiple of 8
                    float cw[2 * TB];                      // cw[j] = c[base-1+j]
#pragma unroll
                    for (int q = 0; q < 4; ++q) {
                        const float4 cv = *reinterpret_cast<const float4*>(cs + (base - 1) + 4 * q);
                        cw[4 * q + 0] = cv.x; cw[4 * q + 1] = cv.y;
                        cw[4 * q + 2] = cv.z; cw[4 * q + 3] = cv.w;
                    }
#pragma unroll
                    for (int kk = 0; kk < TB; ++kk) {
#pragma unroll
                        for (int i = 0; i < TB; ++i)
                            old_[i] += hv[kk] * cw[TB - kk + i];
                    }
                }
            }
        }

        // episode 2: sequential phase, pure VALU + global stores
        float dvb[TB];
#pragma unroll
        for (int i = 0; i < TB; ++i) {
            const int nm1 = n0 + i;
            const float Iv = Ivv[i];
            const float f  = (-0.025f * (V + 70.f) + Iv) * 2.0f;   // /CM, CM=0.5
            const float Vn = kappa * f + V - old_[i];
            const bool  sp = (Vn >= -50.f);
            const float Vr = sp ? -70.f : Vn;
            const float dv = Vr - V;
            dvb[i] = dv;
            dvbits |= __float_as_uint(dv);
#pragma unroll
            for (int i2 = i + 1; i2 < TB; ++i2)
                old_[i2] += dv * cn_[i2 - i];
            if (FINAL) {
                ((float*)spikes)[(size_t)nm1 * NT + nid] = sp ? 1.f : 0.f;
                mems[(size_t)nm1 * NT + nid] = Vr;
            } else {
                ((__hip_bfloat16*)spikes)[(size_t)nm1 * NT + nid] = __float2bfloat16(sp ? 1.f : 0.f);
            }
            V = Vr;
        }

        // episode 3: batch hist writes
        __builtin_amdgcn_sched_barrier(0);
#pragma unroll
        for (int i = 0; i < TB; ++i)
            hist[(n0 + i) * STRIDE + li] = dvb[i];
        __builtin_amdgcn_sched_barrier(0);
    }
}

// --- prep: fused ctab init + data cast/permute + Wh cast (R8, proven) -------
__global__ __launch_bounds__(256) void prep_kernel(const float* __restrict__ data,
                                                   const float* __restrict__ Wh,
                                                   __hip_bfloat16* __restrict__ Ab,
                                                   __hip_bfloat16* __restrict__ Whb,
                                                   float* __restrict__ ctab) {
    const int bid = blockIdx.x;
    if (bid == 0) {
        const int j = threadIdx.x;
        if (j < 192) {
            double a = pow((double)(j + 1), 0.8);
            double b = pow((double)j, 0.8);
            ctab[j] = (float)(a - b);
        }
        return;
    }
    if (bid <= 6400) {
        const int idx = (bid - 1) * 256 + threadIdx.x;      // < M1*200 exactly
        const int r  = idx / 200;
        const int n4 = (idx - r * 200) * 4;
        const int t = r >> 6, b = r & 63;
        const int srow = b * T_STEPS + t;
        ushort4 o;
        if (n4 < NI) {
            const float4 f = *reinterpret_cast<const float4*>(data + (size_t)srow * NI + n4);
            o.x = f2b_bits(f.x); o.y = f2b_bits(f.y); o.z = f2b_bits(f.z); o.w = f2b_bits(f.w);
        } else {
            o.x = o.y = o.z = o.w = 0;
        }
        *reinterpret_cast<ushort4*>(Ab + (size_t)r * NIP + n4) = o;
    } else {
        const int idx = (bid - 6401) * 256 + threadIdx.x;   // < NH*200 exactly
        const int r  = idx / 200;
        const int n4 = (idx - r * 200) * 4;
        ushort4 o;
        if (n4 < NI) {
            const float4 f = *reinterpret_cast<const float4*>(Wh + (size_t)r * NI + n4);
            o.x = f2b_bits(f.x); o.y = f2b_bits(f.y); o.z = f2b_bits(f.z); o.w = f2b_bits(f.w);
        } else {
            o.x = o.y = o.z = o.w = 0;
        }
        *reinterpret_cast<ushort4*>(Whb + (size_t)r * NIP + n4) = o;
    }
}

// ---------------------------------------------------------------------------
// FUSED: GEMM1 + hidden scan. Block (b, hn) computes the 128(time) x 64(h)
// I-tile for batch b / neuron block hn, keeps it in LDS (bf16 — identical
// cast to the old Ih path), then wave 0 scans it and stores spikes straight
// to Sh. Fixes R10's failure modes: inputs are pre-cast bf16 read via
// global_load_lds dbuf (no reg-staging spill), acc is [4][2]=32 VGPRs, LDS
// 72.75 KB -> 2 blocks/CU (keeps R11's drain-overlap).
// A-band rows for batch b are {t*64+b} (stride-64 row pick via per-lane
// global addresses). Linear block id = b + 64*hn => all hn-blocks of a batch
// share an XCD -> the 200 KB A-band is L2-shared.
// K-accumulation order per output element == split version -> bit-identical.
// ---------------------------------------------------------------------------
__global__ __launch_bounds__(256) void fused1_kernel(const __hip_bfloat16* __restrict__ A,
                                                     const __hip_bfloat16* __restrict__ B,
                                                     __hip_bfloat16* __restrict__ Sh,
                                                     const float* __restrict__ ctab,
                                                     float kappa) {
    __shared__ __hip_bfloat16 As[2][128 * 32];   // 16 KB
    __shared__ __hip_bfloat16 Bs[2][64 * 32];    //  8 KB
    __shared__ __hip_bfloat16 Ibuf[128 * 64];    // 16 KB  [t][h]
    __shared__ float          hist[128 * 64];    // 32 KB
    __shared__ __attribute__((aligned(16))) float cs[192];

    const int tid  = threadIdx.x;
    const int wave = tid >> 6, lane = tid & 63;
    const int wm = wave >> 1, wn = wave & 1;     // 2x2 waves over (128 t, 64 h)
    const int b  = blockIdx.x;                   // batch element
    const int hn = blockIdx.y;                   // 64-wide neuron block
    const int lrow = lane >> 2;      // 0..15
    const int lchk = lane & 3;       // 0..3

    const int NTILES = NIP / 32;     // 25

    auto STAGE = [&](int buf, int tt) {
        const int k0 = tt * 32;
#pragma unroll
        for (int p = 0; p < 2; ++p) {   // A tile 128x32: two stripes per wave
            const int rbase = p * 64 + wave * 16;
            // tile row rt=rbase+lrow corresponds to global row rt*64 + b
            const __hip_bfloat16* g = A + (size_t)((rbase + lrow) * 64 + b) * NIP + k0 + lchk * 8;
            __builtin_amdgcn_global_load_lds((const __attribute__((address_space(1))) void*)g,
                                             (__attribute__((address_space(3))) void*)(As[buf] + rbase * 32),
                                             16, 0, 0);
        }
        {   // B tile 64x32: one stripe per wave
            const __hip_bfloat16* g = B + (size_t)(hn * 64 + wave * 16 + lrow) * NIP + k0 + lchk * 8;
            __builtin_amdgcn_global_load_lds((const __attribute__((address_space(1))) void*)g,
                                             (__attribute__((address_space(3))) void*)(Bs[buf] + wave * 16 * 32),
                                             16, 0, 0);
        }
    };

    f32x4 acc[4][2] = {};

    STAGE(0, 0);
    __syncthreads();                 // drains vmcnt(0): buf0 ready

    int cur = 0;
    for (int t = 0; t < NTILES; ++t) {
        if (t + 1 < NTILES) STAGE(cur ^ 1, t + 1);   // loads in flight over MFMA

        short8 a[4], bb[2];
#pragma unroll
        for (int i = 0; i < 4; ++i)
            a[i] = *reinterpret_cast<const short8*>(As[cur] + (wm * 64 + i * 16 + (lane & 15)) * 32 + (lane >> 4) * 8);
#pragma unroll
        for (int j = 0; j < 2; ++j)
            bb[j] = *reinterpret_cast<const short8*>(Bs[cur] + (wn * 32 + j * 16 + (lane & 15)) * 32 + (lane >> 4) * 8);
#pragma unroll
        for (int i = 0; i < 4; ++i)
#pragma unroll
            for (int j = 0; j < 2; ++j)
                acc[i][j] = __builtin_amdgcn_mfma_f32_16x16x32_bf16(a[i], bb[j], acc[i][j], 0, 0, 0);

        __syncthreads();             // drains next-tile loads + all reads of cur
        cur ^= 1;
    }

    // I tile -> LDS bf16 (same cast as the old Ih global write; row=t, col=h)
    // C/D layout: col = lane&15, row = (lane>>4)*4 + reg
#pragma unroll
    for (int i = 0; i < 4; ++i) {
#pragma unroll
        for (int j = 0; j < 2; ++j) {
            const int col = wn * 32 + j * 16 + (lane & 15);
#pragma unroll
            for (int r2 = 0; r2 < 4; ++r2) {
                const int row = wm * 64 + i * 16 + (lane >> 4) * 4 + r2;
                Ibuf[row * 64 + col] = __float2bfloat16(acc[i][j][r2]);
            }
        }
    }
    __syncthreads();                             // Ibuf complete

    for (int j = tid; j < 192; j += 256) cs[j] = ctab[j];
    __syncthreads();

    // hidden scan: wave 0, one thread per neuron column.
    // Store target: Sh[(t*64+b)*NH + hn*64 + lane]
    //   = (Sh + b*NH)[t*(64*NH) + (hn*64 + lane)]
    if (tid < 64) {
        flif_scan_body<false, 64>((const char*)Ibuf, hist, cs,
                                  (void*)(Sh + (size_t)b * NH), nullptr,
                                  64 * NH, hn * 64 + tid, tid, kappa);
    }
}

// --- GEMM2: Io[r][o] = sum_h S[r][h]*Wo[o][h] (R8 version) ------------------
__global__ __launch_bounds__(256) void gemm2_kernel(const __hip_bfloat16* __restrict__ S,
                                                    const float* __restrict__ Wo,
                                                    float* __restrict__ Io) {
    const int wave = threadIdx.x >> 6, lane = threadIdx.x & 63;
    const int r0 = (blockIdx.x * 4 + wave) * 4;

    float wreg[NO][8];
#pragma unroll
    for (int o = 0; o < NO; ++o) {
        const float4 w0 = *reinterpret_cast<const float4*>(Wo + (size_t)o * NH + lane * 8);
        const float4 w1 = *reinterpret_cast<const float4*>(Wo + (size_t)o * NH + lane * 8 + 4);
        wreg[o][0] = w0.x; wreg[o][1] = w0.y; wreg[o][2] = w0.z; wreg[o][3] = w0.w;
        wreg[o][4] = w1.x; wreg[o][5] = w1.y; wreg[o][6] = w1.z; wreg[o][7] = w1.w;
    }

#pragma unroll
    for (int rr = 0; rr < 4; ++rr) {
        const int r = r0 + rr;
        u16x8 raw = *reinterpret_cast<const u16x8*>(S + (size_t)r * NH + lane * 8);
        float s[8];
#pragma unroll
        for (int j = 0; j < 8; ++j) s[j] = b2f_bits(raw[j]);
#pragma unroll
        for (int o = 0; o < NO; ++o) {
            float a = 0.f;
#pragma unroll
            for (int j = 0; j < 8; ++j) a += s[j] * wreg[o][j];
#pragma unroll
            for (int off = 32; off; off >>= 1) a += __shfl_xor(a, off);
            if (lane == o) Io[(size_t)r * NO + o] = a;
        }
    }
}

// --- final scan (R8 version: LDS-staged f32 input, STRIDE=64) ---------------
__global__ __launch_bounds__(64) void flif_final_kernel(const float* __restrict__ Io,
                                                        float* __restrict__ spikes,
                                                        float* __restrict__ mems,
                                                        const float* __restrict__ ctab,
                                                        float kappa) {
    __shared__ float hist[T_STEPS * 64];                       // 32 KB
    __shared__ __attribute__((aligned(16))) float cs[192];
    __shared__ __attribute__((aligned(16))) char inps[T_STEPS * 64 * 4];  // 32 KB
    const int lane = threadIdx.x;
    const int nid  = blockIdx.x * 64 + lane;

#pragma unroll
    for (int q = 0; q < 32; ++q) {
        const float* g = Io +
            ((size_t)(q * 4 + (lane >> 4)) * NT_O + (size_t)blockIdx.x * 64 + (lane & 15) * 4);
        __builtin_amdgcn_global_load_lds((const __attribute__((address_space(1))) void*)g,
                                         (__attribute__((address_space(3))) void*)(inps + q * 1024),
                                         16, 0, 0);
    }
    for (int j = lane; j < 192; j += 64) cs[j] = ctab[j];
    __syncthreads();

    flif_scan_body<true, 64>(inps, hist, cs, spikes, mems, NT_O, nid, lane, kappa);
}

extern "C" void kernel_launch(void* const* d_in, const int* in_sizes, int n_in,
                              void* d_out, int out_size, void* d_ws, size_t ws_size,
                              hipStream_t stream) {
    const float* data = (const float*)d_in[0];   // [64][128][784]
    const float* Wh   = (const float*)d_in[1];   // [512][784]
    const float* Wo   = (const float*)d_in[2];   // [10][512]
    float* out = (float*)d_out;                  // f32: spikes then mems

    char* ws = (char*)d_ws;
    size_t off = 0;
    auto alloc = [&](size_t bytes) { void* p = ws + off; off += (bytes + 255) & ~255ull; return p; };
    __hip_bfloat16* Ab   = (__hip_bfloat16*)alloc((size_t)M1 * NIP * 2);  // 13.1 MB
    __hip_bfloat16* Whb  = (__hip_bfloat16*)alloc((size_t)NH * NIP * 2);  // 0.8 MB
    __hip_bfloat16* Sh   = (__hip_bfloat16*)alloc((size_t)M1 * NH * 2);   // 8.4 MB
    float*          Io   = (float*)alloc((size_t)M1 * NO * 4);            // 0.33 MB
    float*          ctab = (float*)alloc(192 * 4);

    const float kappa = (float)(std::pow(0.1, 0.2) * std::tgamma(1.8));

    prep_kernel<<<6801, 256, 0, stream>>>(data, Wh, Ab, Whb, ctab);

    dim3 g1(BATCH, NH / 64, 1);     // (64, 8) = 512 blocks = 2 blocks/CU
    fused1_kernel<<<g1, 256, 0, stream>>>(Ab, Whb, Sh, ctab, kappa);

    gemm2_kernel<<<M1 / 16, 256, 0, stream>>>(Sh, Wo, Io);

    flif_final_kernel<<<NT_O / 64, 64, 0, stream>>>(Io, out, out + OUT_HALF, ctab, kappa);
}